// Round 8
// baseline (76.501 us; speedup 1.0000x reference)
//
#include <hip/hip_runtime.h>

// CRF loss: mean_b( log Z_b - score_b ),  B=128, S=512, T=64 (mask all-ones).
//
// Parallel associative scan: alpha_511 = alpha_0 * PROD_i (E * diag(eem_i)).
// Phase 1 (crf_chunk_kernel<CH>): nb-SPLIT — each wave propagates 16 basis
//   columns (one nb) of one (batch, chunk) through SC steps of the verified
//   MFMA recurrence: 8 MFMA + ~35 VALU + 16 ds_bpermute per step. 8192 waves.
//   Per-wave (per-16-row-group) exact-pow2 rescale -> eoffs[b][c][nb].
//   A-fragments computed in the prologue (atab kernel folded in).
// Phase 2 (crf_combine_kernel<CH>): one wave per batch; folds the 4 group
//   exponents into alpha (exact pow2), chains alpha through the CH stored
//   bf16 matrices (double-buffered row preload). Score fused.

#define BB 128
#define SS 512
#define TT 64

typedef float f32x4 __attribute__((ext_vector_type(4)));
typedef short s16x8 __attribute__((ext_vector_type(8)));
typedef unsigned int u32x4 __attribute__((ext_vector_type(4)));

#define MFMA16(a, b, c) __builtin_amdgcn_mfma_f32_16x16x32_bf16((a), (b), (c), 0, 0, 0)

#define LOG2E 1.4426950408889634f
#define LN2   0.6931471805599453f

__device__ __forceinline__ unsigned pack_bf16_trunc(float hi, float lo) {
    return __builtin_amdgcn_perm(__float_as_uint(hi), __float_as_uint(lo), 0x07060302u);
}
__device__ __forceinline__ unsigned short bf16_rne(float x) {
    unsigned u = __float_as_uint(x);
    u += 0x7FFFu + ((u >> 16) & 1u);
    return (unsigned short)(u >> 16);
}
__device__ __forceinline__ float rdlane(float v, int lane) {
    return __uint_as_float(__builtin_amdgcn_readlane(__float_as_uint(v), lane));
}
__device__ __forceinline__ float BP(int adr, int src) {
    return __uint_as_float((unsigned)__builtin_amdgcn_ds_bpermute(adr, src));
}

// ---------------- Phase 1: one nb (16 basis rows) per wave ----------------
template<int L>
__device__ __forceinline__ void chunk_body(
    const float* __restrict__ embl, const int sbase, const s16x8 A[4][2],
    const int nb, unsigned short* __restrict__ Mout, int* __restrict__ eoff_out,
    const int g, const int m, const int l)
{
    constexpr int NG = (L - 7) / 8;      // full 8-step groups
    constexpr int TL = L - 8 * NG;       // tail steps (7 or 8)
    static_assert(TL == 7 || TL == 8, "tail");
    const f32x4 Z = {0.f, 0.f, 0.f, 0.f};
    union BU { s16x8 v; unsigned u[4]; };
    BU Blo, Bhi;
    {
        const int K = 16 * nb + m;       // this wave's basis row for lane m
        #pragma unroll
        for (int r = 0; r < 4; ++r) {
            int k0 = 8 * g + 2 * r;
            Blo.u[r] = ((k0 == K) ? 0x3F80u : 0u) | ((k0 + 1 == K) ? 0x3F800000u : 0u);
            int k1 = 32 + 8 * g + 2 * r;
            Bhi.u[r] = ((k1 == K) ? 0x3F80u : 0u) | ((k1 + 1 == K) ? 0x3F800000u : 0u);
        }
    }

    // bpermute byte addresses for the 16 CUR gathers (state*4), loop-invariant
    int adr[4][4];
    #pragma unroll
    for (int t = 0; t < 4; ++t)
        #pragma unroll
        for (int r = 0; r < 4; ++r)
            adr[t][r] = (8 * g + 4 * (t & 1) + r + 32 * (t >> 1)) << 2;

    // per-lane em ring: re[slot] = em[step][l]  (1 dword/lane/step)
    float re[4];
    #pragma unroll
    for (int i = 0; i < 4; ++i) re[i] = embl[(size_t)(sbase + i) * TT];

    f32x4 CA0, CA1, CA2, CA3, CB0, CB1, CB2, CB3;
    f32x4 dfin[4];
    float fixs = 1.0f;
    int eoff = 0;

#define BUILD(NSL, N0, N1, N2, N3) do {                                           \
    float ee_ = __builtin_amdgcn_exp2f(re[NSL] * LOG2E);                          \
    int ei_ = __float_as_int(ee_);                                                \
    N0[0] = BP(adr[0][0], ei_); N0[1] = BP(adr[0][1], ei_);                       \
    N0[2] = BP(adr[0][2], ei_); N0[3] = BP(adr[0][3], ei_);                       \
    N1[0] = BP(adr[1][0], ei_); N1[1] = BP(adr[1][1], ei_);                       \
    N1[2] = BP(adr[1][2], ei_); N1[3] = BP(adr[1][3], ei_);                       \
    N2[0] = BP(adr[2][0], ei_); N2[1] = BP(adr[2][1], ei_);                       \
    N2[2] = BP(adr[2][2], ei_); N2[3] = BP(adr[2][3], ei_);                       \
    N3[0] = BP(adr[3][0], ei_); N3[1] = BP(adr[3][1], ei_);                       \
    N3[2] = BP(adr[3][2], ei_); N3[3] = BP(adr[3][3], ei_);                       \
} while (0)

#define NBODY1(RESC, U0, U1, U2, U3) do {                                         \
    f32x4 c0 = MFMA16(A[0][0], Blo.v, Z);                                         \
    f32x4 c1 = MFMA16(A[1][0], Blo.v, Z);                                         \
    f32x4 c2 = MFMA16(A[2][0], Blo.v, Z);                                         \
    f32x4 c3 = MFMA16(A[3][0], Blo.v, Z);                                         \
    c0 = MFMA16(A[0][1], Bhi.v, c0);                                              \
    c1 = MFMA16(A[1][1], Bhi.v, c1);                                              \
    c2 = MFMA16(A[2][1], Bhi.v, c2);                                              \
    c3 = MFMA16(A[3][1], Bhi.v, c3);                                              \
    c0 *= U0; c1 *= U1; c2 *= U2; c3 *= U3;                                       \
    if (RESC) {                                                                   \
        mx = fmaxf(mx, fmaxf(fmaxf(fmaxf(c0[0], c0[1]), fmaxf(c0[2], c0[3])),     \
                             fmaxf(fmaxf(c1[0], c1[1]), fmaxf(c1[2], c1[3]))));   \
        mx = fmaxf(mx, fmaxf(fmaxf(fmaxf(c2[0], c2[1]), fmaxf(c2[2], c2[3])),     \
                             fmaxf(fmaxf(c3[0], c3[1]), fmaxf(c3[2], c3[3]))));   \
    }                                                                             \
    Blo.u[0] = pack_bf16_trunc(c0[1], c0[0]);                                     \
    Blo.u[1] = pack_bf16_trunc(c0[3], c0[2]);                                     \
    Blo.u[2] = pack_bf16_trunc(c1[1], c1[0]);                                     \
    Blo.u[3] = pack_bf16_trunc(c1[3], c1[2]);                                     \
    Bhi.u[0] = pack_bf16_trunc(c2[1], c2[0]);                                     \
    Bhi.u[1] = pack_bf16_trunc(c2[3], c2[2]);                                     \
    Bhi.u[2] = pack_bf16_trunc(c3[1], c3[0]);                                     \
    Bhi.u[3] = pack_bf16_trunc(c3[3], c3[2]);                                     \
} while (0)

#define STEP(SL, NSL, U0, U1, U2, U3, N0, N1, N2, N3, FIXF, RESCF, PREF, SIDX) do { \
    BUILD(NSL, N0, N1, N2, N3);                                                   \
    if (PREF) re[SL] = embl[(size_t)(SIDX) * TT];                                 \
    if (FIXF) { U0 *= fixs; U1 *= fixs; U2 *= fixs; U3 *= fixs; }                 \
    float mx = 0.f;                                                               \
    NBODY1(RESCF, U0, U1, U2, U3);                                                \
    if (RESCF) {                                                                  \
        mx = fmaxf(mx, __shfl_xor(mx, 1, 64));                                    \
        mx = fmaxf(mx, __shfl_xor(mx, 2, 64));                                    \
        mx = fmaxf(mx, __shfl_xor(mx, 4, 64));                                    \
        mx = fmaxf(mx, __shfl_xor(mx, 8, 64));                                    \
        mx = fmaxf(mx, __shfl_xor(mx, 16, 64));                                   \
        mx = fmaxf(mx, __shfl_xor(mx, 32, 64));                                   \
        int e_ = (__float_as_int(mx) >> 23) - 127;                                \
        eoff += e_;                                                               \
        fixs = __int_as_float((127 - e_) << 23);                                  \
    }                                                                             \
} while (0)

#define FINALC1(U0, U1, U2, U3) do {                                              \
    f32x4 c0 = MFMA16(A[0][0], Blo.v, Z);                                         \
    f32x4 c1 = MFMA16(A[1][0], Blo.v, Z);                                         \
    f32x4 c2 = MFMA16(A[2][0], Blo.v, Z);                                         \
    f32x4 c3 = MFMA16(A[3][0], Blo.v, Z);                                         \
    c0 = MFMA16(A[0][1], Bhi.v, c0);                                              \
    c1 = MFMA16(A[1][1], Bhi.v, c1);                                              \
    c2 = MFMA16(A[2][1], Bhi.v, c2);                                              \
    c3 = MFMA16(A[3][1], Bhi.v, c3);                                              \
    dfin[0] = c0 * U0;                                                            \
    dfin[1] = c1 * U1;                                                            \
    dfin[2] = c2 * U2;                                                            \
    dfin[3] = c3 * U3;                                                            \
} while (0)

    // CUR for step 0 from re[0]
    BUILD(0, CA0, CA1, CA2, CA3);

    #pragma unroll 1
    for (int gi = 0; gi < NG; ++gi) {
        const int s4 = sbase + 8 * gi + 4;
        STEP(0, 1, CA0, CA1, CA2, CA3, CB0, CB1, CB2, CB3, 1, 0, 1, s4 + 0);
        STEP(1, 2, CB0, CB1, CB2, CB3, CA0, CA1, CA2, CA3, 0, 0, 1, s4 + 1);
        STEP(2, 3, CA0, CA1, CA2, CA3, CB0, CB1, CB2, CB3, 0, 0, 1, s4 + 2);
        STEP(3, 0, CB0, CB1, CB2, CB3, CA0, CA1, CA2, CA3, 0, 0, 1, s4 + 3);
        STEP(0, 1, CA0, CA1, CA2, CA3, CB0, CB1, CB2, CB3, 0, 0, 1, s4 + 4);
        STEP(1, 2, CB0, CB1, CB2, CB3, CA0, CA1, CA2, CA3, 0, 0, 1, s4 + 5);
        STEP(2, 3, CA0, CA1, CA2, CA3, CB0, CB1, CB2, CB3, 0, 0, 1, s4 + 6);
        STEP(3, 0, CB0, CB1, CB2, CB3, CA0, CA1, CA2, CA3, 0, 1, 1, s4 + 7);
    }
    {
        const int t4 = sbase + 8 * NG + 4;
        if constexpr (TL == 8) {
            STEP(0, 1, CA0, CA1, CA2, CA3, CB0, CB1, CB2, CB3, 1, 0, 1, t4 + 0);
            STEP(1, 2, CB0, CB1, CB2, CB3, CA0, CA1, CA2, CA3, 0, 0, 1, t4 + 1);
            STEP(2, 3, CA0, CA1, CA2, CA3, CB0, CB1, CB2, CB3, 0, 0, 1, t4 + 2);
            STEP(3, 0, CB0, CB1, CB2, CB3, CA0, CA1, CA2, CA3, 0, 0, 1, t4 + 3);
            STEP(0, 1, CA0, CA1, CA2, CA3, CB0, CB1, CB2, CB3, 0, 0, 0, 0);
            STEP(1, 2, CB0, CB1, CB2, CB3, CA0, CA1, CA2, CA3, 0, 0, 0, 0);
            STEP(2, 3, CA0, CA1, CA2, CA3, CB0, CB1, CB2, CB3, 0, 0, 0, 0);
            FINALC1(CB0, CB1, CB2, CB3);
        } else {  // TL == 7
            STEP(0, 1, CA0, CA1, CA2, CA3, CB0, CB1, CB2, CB3, 1, 0, 1, t4 + 0);
            STEP(1, 2, CB0, CB1, CB2, CB3, CA0, CA1, CA2, CA3, 0, 0, 1, t4 + 1);
            STEP(2, 3, CA0, CA1, CA2, CA3, CB0, CB1, CB2, CB3, 0, 0, 1, t4 + 2);
            STEP(3, 0, CB0, CB1, CB2, CB3, CA0, CA1, CA2, CA3, 0, 0, 0, 0);
            STEP(0, 1, CA0, CA1, CA2, CA3, CB0, CB1, CB2, CB3, 0, 0, 0, 0);
            STEP(1, 2, CB0, CB1, CB2, CB3, CA0, CA1, CA2, CA3, 0, 0, 0, 0);
            FINALC1(CA0, CA1, CA2, CA3);
        }
    }
#undef FINALC1
#undef STEP
#undef NBODY1
#undef BUILD

    // epilogue: per-group exact-pow2 normalize, store 16 rows of M (bf16)
    float mx = 0.f;
    #pragma unroll
    for (int t = 0; t < 4; ++t) {
        f32x4 v = dfin[t];
        mx = fmaxf(mx, fmaxf(fmaxf(v[0], v[1]), fmaxf(v[2], v[3])));
    }
    #pragma unroll
    for (int sh = 1; sh < 64; sh <<= 1) mx = fmaxf(mx, __shfl_xor(mx, sh, 64));
    int e = (__float_as_int(mx) >> 23) - 127;
    eoff += e;
    const float scl = __int_as_float((127 - e) << 23);
    {
        f32x4 d0 = dfin[0] * scl, d1 = dfin[1] * scl;
        f32x4 d2 = dfin[2] * scl, d3 = dfin[3] * scl;
        const int row = (16 * nb + m) * TT;
        u32x4 w0, w1;
        w0[0] = pack_bf16_trunc(d0[1], d0[0]);
        w0[1] = pack_bf16_trunc(d0[3], d0[2]);
        w0[2] = pack_bf16_trunc(d1[1], d1[0]);
        w0[3] = pack_bf16_trunc(d1[3], d1[2]);
        w1[0] = pack_bf16_trunc(d2[1], d2[0]);
        w1[1] = pack_bf16_trunc(d2[3], d2[2]);
        w1[2] = pack_bf16_trunc(d3[1], d3[0]);
        w1[3] = pack_bf16_trunc(d3[3], d3[2]);
        *(u32x4*)(Mout + row + 8 * g)      = w0;
        *(u32x4*)(Mout + row + 32 + 8 * g) = w1;
    }
    if (l == 0) *eoff_out = eoff;
}

template<int CH>
__global__ __launch_bounds__(256, 2) void crf_chunk_kernel(
    const float* __restrict__ emissions, const float* __restrict__ transitions,
    unsigned short* __restrict__ M, int* __restrict__ eoffs)
{
    constexpr int SC = SS / CH;
    const int tid = threadIdx.x;
    const int l = tid & 63;
    const int wv = tid >> 6;
    const int gid = blockIdx.x * 4 + wv;     // wave id
    const int b   = gid / (CH * 4);
    const int rem = gid % (CH * 4);
    const int c   = rem >> 2;
    const int nb  = rem & 3;
    const int g = l >> 4;
    const int m = l & 15;

    // A fragments (verified mapping), computed in-prologue:
    // A[t][h] elem j = bf16(exp(trans[k][ps])), k = 32h+8g+j,
    // ps = 8*(m>>2) + 4*(t&1) + (m&3) + 32*(t>>1)
    s16x8 A[4][2];
    #pragma unroll
    for (int t = 0; t < 4; ++t) {
        const int ps = 8 * (m >> 2) + 4 * (t & 1) + (m & 3) + 32 * (t >> 1);
        #pragma unroll
        for (int h = 0; h < 2; ++h) {
            union { s16x8 v; unsigned short s[8]; } u;
            #pragma unroll
            for (int j = 0; j < 8; ++j) {
                int k = 32 * h + 8 * g + j;
                u.s[j] = bf16_rne(exp2f(transitions[k * TT + ps] * LOG2E));
            }
            A[t][h] = u.v;
        }
    }

    const float* embl = emissions + (size_t)b * SS * TT + l;
    unsigned short* Mout = M + (size_t)(b * CH + c) * (TT * TT);
    int* eo = eoffs + ((b * CH + c) << 2) + nb;
    const int sbase = SC * c + 1;
    if (c == CH - 1) chunk_body<SC - 1>(embl, sbase, A, nb, Mout, eo, g, m, l);
    else             chunk_body<SC>(embl, sbase, A, nb, Mout, eo, g, m, l);
}

// ---------------- Phase 2: score (fused) + chain + logsumexp ----------------
template<int CH>
__global__ __launch_bounds__(64, 1) void crf_combine_kernel(
    const float* __restrict__ emissions, const float* __restrict__ transitions,
    const float* __restrict__ start_t, const float* __restrict__ end_t,
    const int* __restrict__ tags, const unsigned short* __restrict__ M,
    const int* __restrict__ eoffs, float* __restrict__ res)
{
    const int b = blockIdx.x;
    const int j = threadIdx.x;
    const float* em = emissions + (size_t)b * SS * TT;

    // path score
    float sc = 0.f;
    #pragma unroll
    for (int r = 0; r < SS / TT; ++r) {
        int i = j + r * TT;
        int cur = tags[b * SS + i];
        if (i > 0) {
            int prev = tags[b * SS + i - 1];
            sc += transitions[prev * TT + cur] + em[i * TT + cur];
        } else {
            sc += start_t[cur] + em[cur];
        }
    }
    if (j == 0) sc += end_t[tags[b * SS + SS - 1]];
    #pragma unroll
    for (int s = 1; s < 64; s <<= 1) sc += __shfl_xor(sc, s, 64);

    // chain alpha through CH chunk matrices, double-buffered row preload
    float a = exp2f((start_t[j] + em[j]) * LOG2E);
    int eoff = 0;
    const unsigned short* Mb = M + (size_t)b * CH * (TT * TT);
    unsigned bufA[64], bufB[64];

#define LOADC(BUF, c) do {                                                        \
    const unsigned short* Mc_ = Mb + (size_t)(c) * (TT * TT) + j;                 \
    _Pragma("unroll")                                                             \
    for (int k = 0; k < 64; ++k) BUF[k] = (unsigned)Mc_[k * TT];                  \
} while (0)
#define COMPC(BUF, c) do {                                                        \
    const int* ep_ = eoffs + ((b * CH + (c)) << 2);                               \
    int e0_ = ep_[0], e1_ = ep_[1], e2_ = ep_[2], e3_ = ep_[3];                   \
    int em_ = max(max(e0_, e1_), max(e2_, e3_));                                  \
    int eg_ = (j < 32) ? ((j < 16) ? e0_ : e1_) : ((j < 48) ? e2_ : e3_);         \
    int ef_ = 127 + eg_ - em_; ef_ = ef_ < 0 ? 0 : ef_;                           \
    a *= __int_as_float(ef_ << 23);                                               \
    float a0 = 0.f, a1 = 0.f, a2 = 0.f, a3 = 0.f;                                 \
    _Pragma("unroll")                                                             \
    for (int q = 0; q < 16; ++q) {                                                \
        a0 = fmaf(rdlane(a, q),      __uint_as_float(BUF[q]      << 16), a0);     \
        a1 = fmaf(rdlane(a, 16 + q), __uint_as_float(BUF[16 + q] << 16), a1);     \
        a2 = fmaf(rdlane(a, 32 + q), __uint_as_float(BUF[32 + q] << 16), a2);     \
        a3 = fmaf(rdlane(a, 48 + q), __uint_as_float(BUF[48 + q] << 16), a3);     \
    }                                                                             \
    float acc = (a0 + a1) + (a2 + a3);                                            \
    float mxv = acc;                                                              \
    _Pragma("unroll")                                                             \
    for (int sh = 1; sh < 64; sh <<= 1) mxv = fmaxf(mxv, __shfl_xor(mxv, sh, 64));\
    int e_ = (__float_as_int(mxv) >> 23) - 127;                                   \
    a = acc * __int_as_float((127 - e_) << 23);                                   \
    eoff += e_ + em_;                                                             \
} while (0)

    LOADC(bufA, 0);
    #pragma unroll 1
    for (int cp = 0; cp < CH; cp += 2) {
        LOADC(bufB, cp + 1);
        COMPC(bufA, cp);
        if (cp + 2 < CH) LOADC(bufA, cp + 2);
        COMPC(bufB, cp + 1);
    }
#undef COMPC
#undef LOADC

    float v = a * exp2f(end_t[j] * LOG2E);
    #pragma unroll
    for (int sh = 1; sh < 64; sh <<= 1) v += __shfl_xor(v, sh, 64);
    if (j == 0) res[b] = (log2f(v) + (float)eoff) * LN2 - sc;
}

// ---------------- final mean ----------------
__global__ __launch_bounds__(64) void crf_reduce_kernel(
    const float* __restrict__ res, float* __restrict__ out)
{
    int l = threadIdx.x;
    float v = res[l] + res[l + 64];
    #pragma unroll
    for (int s = 1; s < 64; s <<= 1) v += __shfl_xor(v, s, 64);
    if (l == 0) out[0] = v * (1.0f / (float)BB);
}

extern "C" void kernel_launch(void* const* d_in, const int* in_sizes, int n_in,
                              void* d_out, int out_size, void* d_ws, size_t ws_size,
                              hipStream_t stream) {
    const float* emissions   = (const float*)d_in[0];
    const float* transitions = (const float*)d_in[1];
    const float* start_t     = (const float*)d_in[2];
    const float* end_t       = (const float*)d_in[3];
    const int*   tags        = (const int*)d_in[4];

    float* res   = (float*)d_ws;                               // 128 floats
    int*   eoffs = (int*)((char*)d_ws + 512);                  // <= 8192 ints
    unsigned short* M = (unsigned short*)((char*)d_ws + 65536);

    const size_t need16 = 65536 + (size_t)BB * 16 * TT * TT * 2;  // ~16.8 MB
    if (ws_size >= need16) {
        crf_chunk_kernel<16><<<BB * 16, 256, 0, stream>>>(emissions, transitions, M, eoffs);
        crf_combine_kernel<16><<<BB, 64, 0, stream>>>(emissions, transitions, start_t,
                                                      end_t, tags, M, eoffs, res);
    } else {
        crf_chunk_kernel<8><<<BB * 8, 256, 0, stream>>>(emissions, transitions, M, eoffs);
        crf_combine_kernel<8><<<BB, 64, 0, stream>>>(emissions, transitions, start_t,
                                                     end_t, tags, M, eoffs, res);
    }
    crf_reduce_kernel<<<1, 64, 0, stream>>>(res, (float*)d_out);
}

// Round 9
// 73.973 us; speedup vs baseline: 1.0342x; 1.0342x over previous
//
#include <hip/hip_runtime.h>

// CRF loss: mean_b( log Z_b - score_b ),  B=128, S=512, T=64 (mask all-ones).
//
// Parallel associative scan: alpha_511 = alpha_0 * PROD_i (E * diag(eem_i)).
// Phase 1 (crf_chunk_kernel<CH>): FAT wave (R6-verified body): one wave per
//   (batch, chunk) propagates all 64 identity basis columns (4 independent
//   nb-chains = ILP 4) through SC steps; eem built ONCE per step (1 v_exp +
//   16 ds_bpermute, shared by the 4 chains); CUR double-buffered one step
//   ahead; em ring 1 dword/lane/step. CH=32 -> 4096 fat waves = 4/SIMD
//   (R6 was grid-limited at 2/SIMD). A-fragments computed in-prologue.
// Phase 2 (crf_combine_kernel<CH>): one wave per batch; path score fused;
//   chains alpha through CH stored bf16 matrices (double-buffered preload).

#define BB 128
#define SS 512
#define TT 64

typedef float f32x4 __attribute__((ext_vector_type(4)));
typedef short s16x8 __attribute__((ext_vector_type(8)));
typedef unsigned int u32x4 __attribute__((ext_vector_type(4)));

#define MFMA16(a, b, c) __builtin_amdgcn_mfma_f32_16x16x32_bf16((a), (b), (c), 0, 0, 0)

#define LOG2E 1.4426950408889634f
#define LN2   0.6931471805599453f

__device__ __forceinline__ unsigned pack_bf16_trunc(float hi, float lo) {
    return __builtin_amdgcn_perm(__float_as_uint(hi), __float_as_uint(lo), 0x07060302u);
}
__device__ __forceinline__ unsigned short bf16_rne(float x) {
    unsigned u = __float_as_uint(x);
    u += 0x7FFFu + ((u >> 16) & 1u);
    return (unsigned short)(u >> 16);
}
__device__ __forceinline__ float rdlane(float v, int lane) {
    return __uint_as_float(__builtin_amdgcn_readlane(__float_as_uint(v), lane));
}
__device__ __forceinline__ float BP(int adr, int src) {
    return __uint_as_float((unsigned)__builtin_amdgcn_ds_bpermute(adr, src));
}

// ---------------- Phase 1 (R6-verified fat body) ----------------
template<int L>
__device__ __forceinline__ void chunk_body(
    const float* __restrict__ emb, const int sbase, const s16x8 A[4][2],
    unsigned short* __restrict__ Mout, int* __restrict__ eoff_out,
    const int g, const int m, const int l)
{
    constexpr int NG = (L - 7) / 8;      // full 8-step groups
    constexpr int TL = L - 8 * NG;       // tail steps (7 or 8)
    static_assert(TL == 7 || TL == 8, "tail");
    const f32x4 Z = {0.f, 0.f, 0.f, 0.f};
    union BU { s16x8 v; unsigned u[4]; };
    BU Blo[4], Bhi[4];
    #pragma unroll
    for (int nb = 0; nb < 4; ++nb) {
        const int K = 16 * nb + m;
        #pragma unroll
        for (int r = 0; r < 4; ++r) {
            int k0 = 8 * g + 2 * r;
            Blo[nb].u[r] = ((k0 == K) ? 0x3F80u : 0u) | ((k0 + 1 == K) ? 0x3F800000u : 0u);
            int k1 = 32 + 8 * g + 2 * r;
            Bhi[nb].u[r] = ((k1 == K) ? 0x3F80u : 0u) | ((k1 + 1 == K) ? 0x3F800000u : 0u);
        }
    }

    // bpermute byte addresses for the 16 CUR gathers (state*4), loop-invariant
    int adr[4][4];
    #pragma unroll
    for (int t = 0; t < 4; ++t)
        #pragma unroll
        for (int r = 0; r < 4; ++r)
            adr[t][r] = (8 * g + 4 * (t & 1) + r + 32 * (t >> 1)) << 2;

    // per-lane em ring: re[slot] = em[step][l]  (1 dword/lane/step)
    const float* embl = emb + l;
    float re[4];
    #pragma unroll
    for (int i = 0; i < 4; ++i) re[i] = embl[(size_t)(sbase + i) * TT];

    f32x4 CA0, CA1, CA2, CA3, CB0, CB1, CB2, CB3;
    f32x4 dfin[4][4];
    float fixs = 1.0f;
    int eoff = 0;

#define BUILD(NSL, N0, N1, N2, N3) do {                                           \
    float ee_ = __builtin_amdgcn_exp2f(re[NSL] * LOG2E);                          \
    int ei_ = __float_as_int(ee_);                                                \
    N0[0] = BP(adr[0][0], ei_); N0[1] = BP(adr[0][1], ei_);                       \
    N0[2] = BP(adr[0][2], ei_); N0[3] = BP(adr[0][3], ei_);                       \
    N1[0] = BP(adr[1][0], ei_); N1[1] = BP(adr[1][1], ei_);                       \
    N1[2] = BP(adr[1][2], ei_); N1[3] = BP(adr[1][3], ei_);                       \
    N2[0] = BP(adr[2][0], ei_); N2[1] = BP(adr[2][1], ei_);                       \
    N2[2] = BP(adr[2][2], ei_); N2[3] = BP(adr[2][3], ei_);                       \
    N3[0] = BP(adr[3][0], ei_); N3[1] = BP(adr[3][1], ei_);                       \
    N3[2] = BP(adr[3][2], ei_); N3[3] = BP(adr[3][3], ei_);                       \
} while (0)

#define NBODY(NB, RESC, U0, U1, U2, U3) do {                                      \
    f32x4 c0 = MFMA16(A[0][0], Blo[NB].v, Z);                                     \
    f32x4 c1 = MFMA16(A[1][0], Blo[NB].v, Z);                                     \
    f32x4 c2 = MFMA16(A[2][0], Blo[NB].v, Z);                                     \
    f32x4 c3 = MFMA16(A[3][0], Blo[NB].v, Z);                                     \
    c0 = MFMA16(A[0][1], Bhi[NB].v, c0);                                          \
    c1 = MFMA16(A[1][1], Bhi[NB].v, c1);                                          \
    c2 = MFMA16(A[2][1], Bhi[NB].v, c2);                                          \
    c3 = MFMA16(A[3][1], Bhi[NB].v, c3);                                          \
    c0 *= U0; c1 *= U1; c2 *= U2; c3 *= U3;                                       \
    if (RESC) {                                                                   \
        mx = fmaxf(mx, fmaxf(fmaxf(fmaxf(c0[0], c0[1]), fmaxf(c0[2], c0[3])),     \
                             fmaxf(fmaxf(c1[0], c1[1]), fmaxf(c1[2], c1[3]))));   \
        mx = fmaxf(mx, fmaxf(fmaxf(fmaxf(c2[0], c2[1]), fmaxf(c2[2], c2[3])),     \
                             fmaxf(fmaxf(c3[0], c3[1]), fmaxf(c3[2], c3[3]))));   \
    }                                                                             \
    Blo[NB].u[0] = pack_bf16_trunc(c0[1], c0[0]);                                 \
    Blo[NB].u[1] = pack_bf16_trunc(c0[3], c0[2]);                                 \
    Blo[NB].u[2] = pack_bf16_trunc(c1[1], c1[0]);                                 \
    Blo[NB].u[3] = pack_bf16_trunc(c1[3], c1[2]);                                 \
    Bhi[NB].u[0] = pack_bf16_trunc(c2[1], c2[0]);                                 \
    Bhi[NB].u[1] = pack_bf16_trunc(c2[3], c2[2]);                                 \
    Bhi[NB].u[2] = pack_bf16_trunc(c3[1], c3[0]);                                 \
    Bhi[NB].u[3] = pack_bf16_trunc(c3[3], c3[2]);                                 \
} while (0)

#define STEP(SL, NSL, U0, U1, U2, U3, N0, N1, N2, N3, FIXF, RESCF, PREF, SIDX) do { \
    BUILD(NSL, N0, N1, N2, N3);                                                   \
    if (PREF) re[SL] = embl[(size_t)(SIDX) * TT];                                 \
    if (FIXF) { U0 *= fixs; U1 *= fixs; U2 *= fixs; U3 *= fixs; }                 \
    float mx = 0.f;                                                               \
    NBODY(0, RESCF, U0, U1, U2, U3);                                              \
    NBODY(1, RESCF, U0, U1, U2, U3);                                              \
    NBODY(2, RESCF, U0, U1, U2, U3);                                              \
    NBODY(3, RESCF, U0, U1, U2, U3);                                              \
    if (RESCF) {                                                                  \
        mx = fmaxf(mx, __shfl_xor(mx, 1, 64));                                    \
        mx = fmaxf(mx, __shfl_xor(mx, 2, 64));                                    \
        mx = fmaxf(mx, __shfl_xor(mx, 4, 64));                                    \
        mx = fmaxf(mx, __shfl_xor(mx, 8, 64));                                    \
        mx = fmaxf(mx, __shfl_xor(mx, 16, 64));                                   \
        mx = fmaxf(mx, __shfl_xor(mx, 32, 64));                                   \
        int e_ = (__float_as_int(mx) >> 23) - 127;                                \
        eoff += e_;                                                               \
        fixs = __int_as_float((127 - e_) << 23);                                  \
    }                                                                             \
} while (0)

#define FINALC(U0, U1, U2, U3) do {                                               \
    _Pragma("unroll")                                                             \
    for (int nb = 0; nb < 4; ++nb) {                                              \
        f32x4 c0 = MFMA16(A[0][0], Blo[nb].v, Z);                                 \
        f32x4 c1 = MFMA16(A[1][0], Blo[nb].v, Z);                                 \
        f32x4 c2 = MFMA16(A[2][0], Blo[nb].v, Z);                                 \
        f32x4 c3 = MFMA16(A[3][0], Blo[nb].v, Z);                                 \
        c0 = MFMA16(A[0][1], Bhi[nb].v, c0);                                      \
        c1 = MFMA16(A[1][1], Bhi[nb].v, c1);                                      \
        c2 = MFMA16(A[2][1], Bhi[nb].v, c2);                                      \
        c3 = MFMA16(A[3][1], Bhi[nb].v, c3);                                      \
        dfin[nb][0] = c0 * U0;                                                    \
        dfin[nb][1] = c1 * U1;                                                    \
        dfin[nb][2] = c2 * U2;                                                    \
        dfin[nb][3] = c3 * U3;                                                    \
    }                                                                             \
} while (0)

    // CUR for step 0 from re[0]
    BUILD(0, CA0, CA1, CA2, CA3);

    #pragma unroll 1
    for (int gi = 0; gi < NG; ++gi) {
        const int s4 = sbase + 8 * gi + 4;
        STEP(0, 1, CA0, CA1, CA2, CA3, CB0, CB1, CB2, CB3, 1, 0, 1, s4 + 0);
        STEP(1, 2, CB0, CB1, CB2, CB3, CA0, CA1, CA2, CA3, 0, 0, 1, s4 + 1);
        STEP(2, 3, CA0, CA1, CA2, CA3, CB0, CB1, CB2, CB3, 0, 0, 1, s4 + 2);
        STEP(3, 0, CB0, CB1, CB2, CB3, CA0, CA1, CA2, CA3, 0, 0, 1, s4 + 3);
        STEP(0, 1, CA0, CA1, CA2, CA3, CB0, CB1, CB2, CB3, 0, 0, 1, s4 + 4);
        STEP(1, 2, CB0, CB1, CB2, CB3, CA0, CA1, CA2, CA3, 0, 0, 1, s4 + 5);
        STEP(2, 3, CA0, CA1, CA2, CA3, CB0, CB1, CB2, CB3, 0, 0, 1, s4 + 6);
        STEP(3, 0, CB0, CB1, CB2, CB3, CA0, CA1, CA2, CA3, 0, 1, 1, s4 + 7);
    }
    {
        const int t4 = sbase + 8 * NG + 4;
        if constexpr (TL == 8) {
            STEP(0, 1, CA0, CA1, CA2, CA3, CB0, CB1, CB2, CB3, 1, 0, 1, t4 + 0);
            STEP(1, 2, CB0, CB1, CB2, CB3, CA0, CA1, CA2, CA3, 0, 0, 1, t4 + 1);
            STEP(2, 3, CA0, CA1, CA2, CA3, CB0, CB1, CB2, CB3, 0, 0, 1, t4 + 2);
            STEP(3, 0, CB0, CB1, CB2, CB3, CA0, CA1, CA2, CA3, 0, 0, 1, t4 + 3);
            STEP(0, 1, CA0, CA1, CA2, CA3, CB0, CB1, CB2, CB3, 0, 0, 0, 0);
            STEP(1, 2, CB0, CB1, CB2, CB3, CA0, CA1, CA2, CA3, 0, 0, 0, 0);
            STEP(2, 3, CA0, CA1, CA2, CA3, CB0, CB1, CB2, CB3, 0, 0, 0, 0);
            FINALC(CB0, CB1, CB2, CB3);
        } else {  // TL == 7
            STEP(0, 1, CA0, CA1, CA2, CA3, CB0, CB1, CB2, CB3, 1, 0, 1, t4 + 0);
            STEP(1, 2, CB0, CB1, CB2, CB3, CA0, CA1, CA2, CA3, 0, 0, 1, t4 + 1);
            STEP(2, 3, CA0, CA1, CA2, CA3, CB0, CB1, CB2, CB3, 0, 0, 1, t4 + 2);
            STEP(3, 0, CB0, CB1, CB2, CB3, CA0, CA1, CA2, CA3, 0, 0, 0, 0);
            STEP(0, 1, CA0, CA1, CA2, CA3, CB0, CB1, CB2, CB3, 0, 0, 0, 0);
            STEP(1, 2, CB0, CB1, CB2, CB3, CA0, CA1, CA2, CA3, 0, 0, 0, 0);
            FINALC(CA0, CA1, CA2, CA3);
        }
    }
#undef FINALC
#undef STEP
#undef NBODY
#undef BUILD

    // epilogue: exact-pow2 normalize, store M[k][j] bf16
    float mx = 0.f;
    #pragma unroll
    for (int nb = 0; nb < 4; ++nb)
        #pragma unroll
        for (int t = 0; t < 4; ++t) {
            f32x4 v = dfin[nb][t];
            mx = fmaxf(mx, fmaxf(fmaxf(v[0], v[1]), fmaxf(v[2], v[3])));
        }
    #pragma unroll
    for (int sh = 1; sh < 64; sh <<= 1) mx = fmaxf(mx, __shfl_xor(mx, sh, 64));
    int e = (__float_as_int(mx) >> 23) - 127;
    eoff += e;
    const float scl = __int_as_float((127 - e) << 23);
    #pragma unroll
    for (int nb = 0; nb < 4; ++nb) {
        f32x4 d0 = dfin[nb][0] * scl, d1 = dfin[nb][1] * scl;
        f32x4 d2 = dfin[nb][2] * scl, d3 = dfin[nb][3] * scl;
        const int row = (16 * nb + m) * TT;
        u32x4 w0, w1;
        w0[0] = pack_bf16_trunc(d0[1], d0[0]);
        w0[1] = pack_bf16_trunc(d0[3], d0[2]);
        w0[2] = pack_bf16_trunc(d1[1], d1[0]);
        w0[3] = pack_bf16_trunc(d1[3], d1[2]);
        w1[0] = pack_bf16_trunc(d2[1], d2[0]);
        w1[1] = pack_bf16_trunc(d2[3], d2[2]);
        w1[2] = pack_bf16_trunc(d3[1], d3[0]);
        w1[3] = pack_bf16_trunc(d3[3], d3[2]);
        *(u32x4*)(Mout + row + 8 * g)      = w0;
        *(u32x4*)(Mout + row + 32 + 8 * g) = w1;
    }
    if (l == 0) *eoff_out = eoff;
}

template<int CH>
__global__ __launch_bounds__(256, 2) void crf_chunk_kernel(
    const float* __restrict__ emissions, const float* __restrict__ transitions,
    unsigned short* __restrict__ M, int* __restrict__ eoffs)
{
    constexpr int SC = SS / CH;
    const int tid = threadIdx.x;
    const int l = tid & 63;
    const int w = tid >> 6;
    const int g = l >> 4;
    const int m = l & 15;
    const int b = blockIdx.x / (CH / 4);
    const int c = (blockIdx.x % (CH / 4)) * 4 + w;
    const float* emb = emissions + (size_t)b * SS * TT;

    // A fragments (verified mapping), in-prologue:
    // A[t][h] elem j = bf16(exp(trans[k][ps])), k = 32h+8g+j,
    // ps = 8*(m>>2) + 4*(t&1) + (m&3) + 32*(t>>1)
    s16x8 A[4][2];
    #pragma unroll
    for (int t = 0; t < 4; ++t) {
        const int ps = 8 * (m >> 2) + 4 * (t & 1) + (m & 3) + 32 * (t >> 1);
        #pragma unroll
        for (int h = 0; h < 2; ++h) {
            union { s16x8 v; unsigned short s[8]; } u;
            #pragma unroll
            for (int j = 0; j < 8; ++j) {
                int k = 32 * h + 8 * g + j;
                u.s[j] = bf16_rne(exp2f(transitions[k * TT + ps] * LOG2E));
            }
            A[t][h] = u.v;
        }
    }

    unsigned short* Mout = M + (size_t)(b * CH + c) * (TT * TT);
    int* eo = eoffs + b * CH + c;
    const int sbase = SC * c + 1;
    if (c == CH - 1) chunk_body<SC - 1>(emb, sbase, A, Mout, eo, g, m, l);
    else             chunk_body<SC>(emb, sbase, A, Mout, eo, g, m, l);
}

// ---------------- Phase 2: score (fused) + chain + logsumexp ----------------
template<int CH>
__global__ __launch_bounds__(64, 1) void crf_combine_kernel(
    const float* __restrict__ emissions, const float* __restrict__ transitions,
    const float* __restrict__ start_t, const float* __restrict__ end_t,
    const int* __restrict__ tags, const unsigned short* __restrict__ M,
    const int* __restrict__ eoffs, float* __restrict__ res)
{
    const int b = blockIdx.x;
    const int j = threadIdx.x;
    const float* em = emissions + (size_t)b * SS * TT;

    // path score
    float sc = 0.f;
    #pragma unroll
    for (int r = 0; r < SS / TT; ++r) {
        int i = j + r * TT;
        int cur = tags[b * SS + i];
        if (i > 0) {
            int prev = tags[b * SS + i - 1];
            sc += transitions[prev * TT + cur] + em[i * TT + cur];
        } else {
            sc += start_t[cur] + em[cur];
        }
    }
    if (j == 0) sc += end_t[tags[b * SS + SS - 1]];
    #pragma unroll
    for (int s = 1; s < 64; s <<= 1) sc += __shfl_xor(sc, s, 64);

    // chain alpha through CH chunk matrices, double-buffered row preload
    float a = exp2f((start_t[j] + em[j]) * LOG2E);
    int eoff = 0;
    const unsigned short* Mb = M + (size_t)b * CH * (TT * TT);
    unsigned bufA[64], bufB[64];

#define LOADC(BUF, c) do {                                                        \
    const unsigned short* Mc_ = Mb + (size_t)(c) * (TT * TT) + j;                 \
    _Pragma("unroll")                                                             \
    for (int k = 0; k < 64; ++k) BUF[k] = (unsigned)Mc_[k * TT];                  \
} while (0)
#define COMPC(BUF, c) do {                                                        \
    float a0 = 0.f, a1 = 0.f, a2 = 0.f, a3 = 0.f;                                 \
    _Pragma("unroll")                                                             \
    for (int q = 0; q < 16; ++q) {                                                \
        a0 = fmaf(rdlane(a, q),      __uint_as_float(BUF[q]      << 16), a0);     \
        a1 = fmaf(rdlane(a, 16 + q), __uint_as_float(BUF[16 + q] << 16), a1);     \
        a2 = fmaf(rdlane(a, 32 + q), __uint_as_float(BUF[32 + q] << 16), a2);     \
        a3 = fmaf(rdlane(a, 48 + q), __uint_as_float(BUF[48 + q] << 16), a3);     \
    }                                                                             \
    float acc = (a0 + a1) + (a2 + a3);                                            \
    float mxv = acc;                                                              \
    _Pragma("unroll")                                                             \
    for (int sh = 1; sh < 64; sh <<= 1) mxv = fmaxf(mxv, __shfl_xor(mxv, sh, 64));\
    int e_ = (__float_as_int(mxv) >> 23) - 127;                                   \
    a = acc * __int_as_float((127 - e_) << 23);                                   \
    eoff += e_ + eoffs[b * CH + (c)];                                             \
} while (0)

    LOADC(bufA, 0);
    #pragma unroll 1
    for (int cp = 0; cp < CH; cp += 2) {
        LOADC(bufB, cp + 1);
        COMPC(bufA, cp);
        if (cp + 2 < CH) LOADC(bufA, cp + 2);
        COMPC(bufB, cp + 1);
    }
#undef COMPC
#undef LOADC

    float v = a * exp2f(end_t[j] * LOG2E);
    #pragma unroll
    for (int sh = 1; sh < 64; sh <<= 1) v += __shfl_xor(v, sh, 64);
    if (j == 0) res[b] = (log2f(v) + (float)eoff) * LN2 - sc;
}

// ---------------- final mean ----------------
__global__ __launch_bounds__(64) void crf_reduce_kernel(
    const float* __restrict__ res, float* __restrict__ out)
{
    int l = threadIdx.x;
    float v = res[l] + res[l + 64];
    #pragma unroll
    for (int s = 1; s < 64; s <<= 1) v += __shfl_xor(v, s, 64);
    if (l == 0) out[0] = v * (1.0f / (float)BB);
}

extern "C" void kernel_launch(void* const* d_in, const int* in_sizes, int n_in,
                              void* d_out, int out_size, void* d_ws, size_t ws_size,
                              hipStream_t stream) {
    const float* emissions   = (const float*)d_in[0];
    const float* transitions = (const float*)d_in[1];
    const float* start_t     = (const float*)d_in[2];
    const float* end_t       = (const float*)d_in[3];
    const int*   tags        = (const int*)d_in[4];

    float* res   = (float*)d_ws;                               // 128 floats
    int*   eoffs = (int*)((char*)d_ws + 512);                  // <= 4096 ints
    unsigned short* M = (unsigned short*)((char*)d_ws + 65536);

    const size_t need32 = 65536 + (size_t)BB * 32 * TT * TT * 2;  // ~33.6 MB
    const size_t need16 = 65536 + (size_t)BB * 16 * TT * TT * 2;  // ~16.8 MB
    if (ws_size >= need32) {
        crf_chunk_kernel<32><<<BB * 8, 256, 0, stream>>>(emissions, transitions, M, eoffs);
        crf_combine_kernel<32><<<BB, 64, 0, stream>>>(emissions, transitions, start_t,
                                                      end_t, tags, M, eoffs, res);
    } else if (ws_size >= need16) {
        crf_chunk_kernel<16><<<BB * 4, 256, 0, stream>>>(emissions, transitions, M, eoffs);
        crf_combine_kernel<16><<<BB, 64, 0, stream>>>(emissions, transitions, start_t,
                                                      end_t, tags, M, eoffs, res);
    } else {
        crf_chunk_kernel<8><<<BB * 2, 256, 0, stream>>>(emissions, transitions, M, eoffs);
        crf_combine_kernel<8><<<BB, 64, 0, stream>>>(emissions, transitions, start_t,
                                                     end_t, tags, M, eoffs, res);
    }
    crf_reduce_kernel<<<1, 64, 0, stream>>>(res, (float*)d_out);
}

// Round 11
// 56.325 us; speedup vs baseline: 1.3582x; 1.3133x over previous
//
#include <hip/hip_runtime.h>

// CRF loss: mean_b( log Z_b - score_b ),  B=128, S=512, T=64 (mask all-ones).
//
// Parallel associative scan: alpha_511 = alpha_0 * PROD_i (E * diag(eem_i)).
// Phase 0 (crf_atab_kernel): per-lane A-fragment table (16 KB), R6-verified.
// Phase 1 (crf_chunk_kernel<CH>): per (batch, chunk) fat wave runs the
//   verified MFMA recurrence on 64 identity basis columns; eem built once per
//   step (1 v_exp + 16 ds_bpermute), CUR double-buffered; em ring 1 dword/
//   lane/step. M stored UNNORMALIZED bf16 (exact-pow2 scaling commutes with
//   truncation -> mantissas identical to normalized version; in-loop rescale
//   bounds entries < 2^110). No fences, no cross-block traffic.
// Phase 2 (crf_combine_kernel<CH>): one 4-wave BLOCK per batch: score 4-wave
//   split; alpha chain with per-wave 16-row k-split, LDS partial sums,
//   4-buffer static-index prefetch ring. Launch boundary = the sync.
// Phase 3: mean reduce.

#define BB 128
#define SS 512
#define TT 64

typedef float f32x4 __attribute__((ext_vector_type(4)));
typedef short s16x8 __attribute__((ext_vector_type(8)));
typedef unsigned int u32x4 __attribute__((ext_vector_type(4)));

#define MFMA16(a, b, c) __builtin_amdgcn_mfma_f32_16x16x32_bf16((a), (b), (c), 0, 0, 0)

#define LOG2E 1.4426950408889634f
#define LN2   0.6931471805599453f

__device__ __forceinline__ unsigned pack_bf16_trunc(float hi, float lo) {
    return __builtin_amdgcn_perm(__float_as_uint(hi), __float_as_uint(lo), 0x07060302u);
}
__device__ __forceinline__ unsigned short bf16_rne(float x) {
    unsigned u = __float_as_uint(x);
    u += 0x7FFFu + ((u >> 16) & 1u);
    return (unsigned short)(u >> 16);
}
__device__ __forceinline__ float rdlane(float v, int lane) {
    return __uint_as_float(__builtin_amdgcn_readlane(__float_as_uint(v), lane));
}
__device__ __forceinline__ float BP(int adr, int src) {
    return __uint_as_float((unsigned)__builtin_amdgcn_ds_bpermute(adr, src));
}

// ---------------- Phase 0: A-fragment table (R6-verified) ----------------
__global__ __launch_bounds__(64) void crf_atab_kernel(
    const float* __restrict__ transitions, unsigned short* __restrict__ atab)
{
    const int l = threadIdx.x;
    const int g = l >> 4;
    const int m = l & 15;
    #pragma unroll
    for (int t = 0; t < 4; ++t) {
        const int ps = 8 * (m >> 2) + 4 * (t & 1) + (m & 3) + 32 * (t >> 1);
        #pragma unroll
        for (int h = 0; h < 2; ++h) {
            #pragma unroll
            for (int j = 0; j < 8; ++j) {
                int k = 32 * h + 8 * g + j;
                atab[((t * 2 + h) * 64 + l) * 8 + j] =
                    bf16_rne(exp2f(transitions[k * TT + ps] * LOG2E));
            }
        }
    }
}

// ---------------- Phase 1 chunk body (R6 body, final-normalize removed) ----------------
template<int L>
__device__ __forceinline__ void chunk_body(
    const float* __restrict__ embl, const int sbase, const s16x8 A[4][2],
    unsigned short* __restrict__ Mout, int* __restrict__ eoff_out,
    const int g, const int m, const int l)
{
    constexpr int NG = (L - 7) / 8;
    constexpr int TL = L - 8 * NG;
    static_assert(TL == 7 || TL == 8, "tail");
    const f32x4 Z = {0.f, 0.f, 0.f, 0.f};
    union BU { s16x8 v; unsigned u[4]; };
    BU Blo[4], Bhi[4];
    #pragma unroll
    for (int nb = 0; nb < 4; ++nb) {
        const int K = 16 * nb + m;
        #pragma unroll
        for (int r = 0; r < 4; ++r) {
            int k0 = 8 * g + 2 * r;
            Blo[nb].u[r] = ((k0 == K) ? 0x3F80u : 0u) | ((k0 + 1 == K) ? 0x3F800000u : 0u);
            int k1 = 32 + 8 * g + 2 * r;
            Bhi[nb].u[r] = ((k1 == K) ? 0x3F80u : 0u) | ((k1 + 1 == K) ? 0x3F800000u : 0u);
        }
    }

    int adr[4][4];
    #pragma unroll
    for (int t = 0; t < 4; ++t)
        #pragma unroll
        for (int r = 0; r < 4; ++r)
            adr[t][r] = (8 * g + 4 * (t & 1) + r + 32 * (t >> 1)) << 2;

    float re[4];
    #pragma unroll
    for (int i = 0; i < 4; ++i) re[i] = embl[(size_t)(sbase + i) * TT];

    f32x4 CA0, CA1, CA2, CA3, CB0, CB1, CB2, CB3;
    float fixs = 1.0f;
    int eoff = 0;

#define BUILD(NSL, N0, N1, N2, N3) do {                                           \
    float ee_ = __builtin_amdgcn_exp2f(re[NSL] * LOG2E);                          \
    int ei_ = __float_as_int(ee_);                                                \
    N0[0] = BP(adr[0][0], ei_); N0[1] = BP(adr[0][1], ei_);                       \
    N0[2] = BP(adr[0][2], ei_); N0[3] = BP(adr[0][3], ei_);                       \
    N1[0] = BP(adr[1][0], ei_); N1[1] = BP(adr[1][1], ei_);                       \
    N1[2] = BP(adr[1][2], ei_); N1[3] = BP(adr[1][3], ei_);                       \
    N2[0] = BP(adr[2][0], ei_); N2[1] = BP(adr[2][1], ei_);                       \
    N2[2] = BP(adr[2][2], ei_); N2[3] = BP(adr[2][3], ei_);                       \
    N3[0] = BP(adr[3][0], ei_); N3[1] = BP(adr[3][1], ei_);                       \
    N3[2] = BP(adr[3][2], ei_); N3[3] = BP(adr[3][3], ei_);                       \
} while (0)

#define NBODY(NB, RESC, U0, U1, U2, U3) do {                                      \
    f32x4 c0 = MFMA16(A[0][0], Blo[NB].v, Z);                                     \
    f32x4 c1 = MFMA16(A[1][0], Blo[NB].v, Z);                                     \
    f32x4 c2 = MFMA16(A[2][0], Blo[NB].v, Z);                                     \
    f32x4 c3 = MFMA16(A[3][0], Blo[NB].v, Z);                                     \
    c0 = MFMA16(A[0][1], Bhi[NB].v, c0);                                          \
    c1 = MFMA16(A[1][1], Bhi[NB].v, c1);                                          \
    c2 = MFMA16(A[2][1], Bhi[NB].v, c2);                                          \
    c3 = MFMA16(A[3][1], Bhi[NB].v, c3);                                          \
    c0 *= U0; c1 *= U1; c2 *= U2; c3 *= U3;                                       \
    if (RESC) {                                                                   \
        mx = fmaxf(mx, fmaxf(fmaxf(fmaxf(c0[0], c0[1]), fmaxf(c0[2], c0[3])),     \
                             fmaxf(fmaxf(c1[0], c1[1]), fmaxf(c1[2], c1[3]))));   \
        mx = fmaxf(mx, fmaxf(fmaxf(fmaxf(c2[0], c2[1]), fmaxf(c2[2], c2[3])),     \
                             fmaxf(fmaxf(c3[0], c3[1]), fmaxf(c3[2], c3[3]))));   \
    }                                                                             \
    Blo[NB].u[0] = pack_bf16_trunc(c0[1], c0[0]);                                 \
    Blo[NB].u[1] = pack_bf16_trunc(c0[3], c0[2]);                                 \
    Blo[NB].u[2] = pack_bf16_trunc(c1[1], c1[0]);                                 \
    Blo[NB].u[3] = pack_bf16_trunc(c1[3], c1[2]);                                 \
    Bhi[NB].u[0] = pack_bf16_trunc(c2[1], c2[0]);                                 \
    Bhi[NB].u[1] = pack_bf16_trunc(c2[3], c2[2]);                                 \
    Bhi[NB].u[2] = pack_bf16_trunc(c3[1], c3[0]);                                 \
    Bhi[NB].u[3] = pack_bf16_trunc(c3[3], c3[2]);                                 \
} while (0)

#define STEP(SL, NSL, U0, U1, U2, U3, N0, N1, N2, N3, FIXF, RESCF, PREF, SIDX) do { \
    BUILD(NSL, N0, N1, N2, N3);                                                   \
    if (PREF) re[SL] = embl[(size_t)(SIDX) * TT];                                 \
    if (FIXF) { U0 *= fixs; U1 *= fixs; U2 *= fixs; U3 *= fixs; }                 \
    float mx = 0.f;                                                               \
    NBODY(0, RESCF, U0, U1, U2, U3);                                              \
    NBODY(1, RESCF, U0, U1, U2, U3);                                              \
    NBODY(2, RESCF, U0, U1, U2, U3);                                              \
    NBODY(3, RESCF, U0, U1, U2, U3);                                              \
    if (RESCF) {                                                                  \
        mx = fmaxf(mx, __shfl_xor(mx, 1, 64));                                    \
        mx = fmaxf(mx, __shfl_xor(mx, 2, 64));                                    \
        mx = fmaxf(mx, __shfl_xor(mx, 4, 64));                                    \
        mx = fmaxf(mx, __shfl_xor(mx, 8, 64));                                    \
        mx = fmaxf(mx, __shfl_xor(mx, 16, 64));                                   \
        mx = fmaxf(mx, __shfl_xor(mx, 32, 64));                                   \
        int e_ = (__float_as_int(mx) >> 23) - 127;                                \
        eoff += e_;                                                               \
        fixs = __int_as_float((127 - e_) << 23);                                  \
    }                                                                             \
} while (0)

#define FINSTORE(U0, U1, U2, U3) do {                                             \
    _Pragma("unroll")                                                             \
    for (int nb = 0; nb < 4; ++nb) {                                              \
        f32x4 c0 = MFMA16(A[0][0], Blo[nb].v, Z);                                 \
        f32x4 c1 = MFMA16(A[1][0], Blo[nb].v, Z);                                 \
        f32x4 c2 = MFMA16(A[2][0], Blo[nb].v, Z);                                 \
        f32x4 c3 = MFMA16(A[3][0], Blo[nb].v, Z);                                 \
        c0 = MFMA16(A[0][1], Bhi[nb].v, c0);                                      \
        c1 = MFMA16(A[1][1], Bhi[nb].v, c1);                                      \
        c2 = MFMA16(A[2][1], Bhi[nb].v, c2);                                      \
        c3 = MFMA16(A[3][1], Bhi[nb].v, c3);                                      \
        c0 *= U0; c1 *= U1; c2 *= U2; c3 *= U3;                                   \
        const int row = (16 * nb + m) * TT;                                       \
        u32x4 w0, w1;                                                             \
        w0[0] = pack_bf16_trunc(c0[1], c0[0]);                                    \
        w0[1] = pack_bf16_trunc(c0[3], c0[2]);                                    \
        w0[2] = pack_bf16_trunc(c1[1], c1[0]);                                    \
        w0[3] = pack_bf16_trunc(c1[3], c1[2]);                                    \
        w1[0] = pack_bf16_trunc(c2[1], c2[0]);                                    \
        w1[1] = pack_bf16_trunc(c2[3], c2[2]);                                    \
        w1[2] = pack_bf16_trunc(c3[1], c3[0]);                                    \
        w1[3] = pack_bf16_trunc(c3[3], c3[2]);                                    \
        *(u32x4*)(Mout + row + 8 * g)      = w0;                                  \
        *(u32x4*)(Mout + row + 32 + 8 * g) = w1;                                  \
    }                                                                             \
} while (0)

    BUILD(0, CA0, CA1, CA2, CA3);

    #pragma unroll 1
    for (int gi = 0; gi < NG; ++gi) {
        const int s4 = sbase + 8 * gi + 4;
        STEP(0, 1, CA0, CA1, CA2, CA3, CB0, CB1, CB2, CB3, 1, 0, 1, s4 + 0);
        STEP(1, 2, CB0, CB1, CB2, CB3, CA0, CA1, CA2, CA3, 0, 0, 1, s4 + 1);
        STEP(2, 3, CA0, CA1, CA2, CA3, CB0, CB1, CB2, CB3, 0, 0, 1, s4 + 2);
        STEP(3, 0, CB0, CB1, CB2, CB3, CA0, CA1, CA2, CA3, 0, 0, 1, s4 + 3);
        STEP(0, 1, CA0, CA1, CA2, CA3, CB0, CB1, CB2, CB3, 0, 0, 1, s4 + 4);
        STEP(1, 2, CB0, CB1, CB2, CB3, CA0, CA1, CA2, CA3, 0, 0, 1, s4 + 5);
        STEP(2, 3, CA0, CA1, CA2, CA3, CB0, CB1, CB2, CB3, 0, 0, 1, s4 + 6);
        STEP(3, 0, CB0, CB1, CB2, CB3, CA0, CA1, CA2, CA3, 0, 1, 1, s4 + 7);
    }
    {
        const int t4 = sbase + 8 * NG + 4;
        if constexpr (TL == 8) {
            STEP(0, 1, CA0, CA1, CA2, CA3, CB0, CB1, CB2, CB3, 1, 0, 1, t4 + 0);
            STEP(1, 2, CB0, CB1, CB2, CB3, CA0, CA1, CA2, CA3, 0, 0, 1, t4 + 1);
            STEP(2, 3, CA0, CA1, CA2, CA3, CB0, CB1, CB2, CB3, 0, 0, 1, t4 + 2);
            STEP(3, 0, CB0, CB1, CB2, CB3, CA0, CA1, CA2, CA3, 0, 0, 1, t4 + 3);
            STEP(0, 1, CA0, CA1, CA2, CA3, CB0, CB1, CB2, CB3, 0, 0, 0, 0);
            STEP(1, 2, CB0, CB1, CB2, CB3, CA0, CA1, CA2, CA3, 0, 0, 0, 0);
            STEP(2, 3, CA0, CA1, CA2, CA3, CB0, CB1, CB2, CB3, 0, 0, 0, 0);
            FINSTORE(CB0, CB1, CB2, CB3);
        } else {  // TL == 7
            STEP(0, 1, CA0, CA1, CA2, CA3, CB0, CB1, CB2, CB3, 1, 0, 1, t4 + 0);
            STEP(1, 2, CB0, CB1, CB2, CB3, CA0, CA1, CA2, CA3, 0, 0, 1, t4 + 1);
            STEP(2, 3, CA0, CA1, CA2, CA3, CB0, CB1, CB2, CB3, 0, 0, 1, t4 + 2);
            STEP(3, 0, CB0, CB1, CB2, CB3, CA0, CA1, CA2, CA3, 0, 0, 0, 0);
            STEP(0, 1, CA0, CA1, CA2, CA3, CB0, CB1, CB2, CB3, 0, 0, 0, 0);
            STEP(1, 2, CB0, CB1, CB2, CB3, CA0, CA1, CA2, CA3, 0, 0, 0, 0);
            FINSTORE(CA0, CA1, CA2, CA3);
        }
    }
#undef FINSTORE
#undef STEP
#undef NBODY
#undef BUILD

    if (l == 0) *eoff_out = eoff;
}

template<int CH>
__global__ __launch_bounds__(256, 2) void crf_chunk_kernel(
    const float* __restrict__ emissions, const unsigned short* __restrict__ atab,
    unsigned short* __restrict__ M, int* __restrict__ eoffs)
{
    constexpr int SC = SS / CH;
    const int tid = threadIdx.x;
    const int l = tid & 63;
    const int w = tid >> 6;
    const int g = l >> 4;
    const int m = l & 15;
    const int b = blockIdx.x / (CH / 4);
    const int c = (blockIdx.x % (CH / 4)) * 4 + w;

    // A fragments from precomputed table: 8 coalesced 16B loads (L2-hot)
    s16x8 A[4][2];
    #pragma unroll
    for (int t = 0; t < 4; ++t)
        #pragma unroll
        for (int h = 0; h < 2; ++h)
            A[t][h] = *(const s16x8*)(atab + ((t * 2 + h) * 64 + l) * 8);

    const float* embl = emissions + (size_t)b * SS * TT + l;
    unsigned short* Mout = M + (size_t)(b * CH + c) * (TT * TT);
    int* eo = eoffs + b * CH + c;
    const int sbase = SC * c + 1;
    if (c == CH - 1) chunk_body<SC - 1>(embl, sbase, A, Mout, eo, g, m, l);
    else             chunk_body<SC>(embl, sbase, A, Mout, eo, g, m, l);
}

// ---------------- Phase 2: 4-wave block per batch ----------------
template<int CH>
__global__ __launch_bounds__(256, 2) void crf_combine_kernel(
    const float* __restrict__ emissions, const float* __restrict__ transitions,
    const float* __restrict__ start_t, const float* __restrict__ end_t,
    const int* __restrict__ tags, const unsigned short* __restrict__ M,
    const int* __restrict__ eoffs, float* __restrict__ res)
{
    __shared__ float part[4][64];
    __shared__ float scpart[4];
    const int tid = threadIdx.x;
    const int l = tid & 63;
    const int w = tid >> 6;
    const int b = blockIdx.x;
    const float* em = emissions + (size_t)b * SS * TT;

    // ---- path score (4-wave split over timesteps) ----
    {
        float sc = 0.f;
        #pragma unroll
        for (int rr = 0; rr < 2; ++rr) {
            int i = l + (2 * w + rr) * 64;
            int cur = tags[b * SS + i];
            if (i > 0) {
                int prev = tags[b * SS + i - 1];
                sc += transitions[prev * TT + cur] + em[i * TT + cur];
            } else {
                sc += start_t[cur] + em[cur];
            }
        }
        if (tid == 0) sc += end_t[tags[b * SS + SS - 1]];
        #pragma unroll
        for (int s = 1; s < 64; s <<= 1) sc += __shfl_xor(sc, s, 64);
        if (l == 0) scpart[w] = sc;
    }

    // ---- chain alpha through CH chunk matrices (4-wave k-split) ----
    float a = exp2f((start_t[l] + em[l]) * LOG2E);
    int eoff = 0;
    const unsigned short* Mb = M + (size_t)b * CH * (TT * TT);
    unsigned bf0[16], bf1[16], bf2[16], bf3[16];

#define LOADW(BUF, cc) do {                                                       \
    int c_ = (cc) < CH ? (cc) : CH - 1;                                           \
    const unsigned short* Mp_ = Mb + (size_t)c_ * (TT * TT) + (16 * w) * TT + l;  \
    _Pragma("unroll")                                                             \
    for (int q = 0; q < 16; ++q) BUF[q] = (unsigned)Mp_[q * TT];                  \
} while (0)
#define COMPW(BUF, cc) do {                                                       \
    float p_ = 0.f;                                                               \
    _Pragma("unroll")                                                             \
    for (int q = 0; q < 16; ++q)                                                  \
        p_ = fmaf(rdlane(a, 16 * w + q), __uint_as_float(BUF[q] << 16), p_);      \
    part[w][l] = p_;                                                              \
    __syncthreads();                                                              \
    float acc = (part[0][l] + part[1][l]) + (part[2][l] + part[3][l]);            \
    __syncthreads();                                                              \
    float mxv = acc;                                                              \
    _Pragma("unroll")                                                             \
    for (int sh = 1; sh < 64; sh <<= 1) mxv = fmaxf(mxv, __shfl_xor(mxv, sh, 64));\
    int e_ = (__float_as_int(mxv) >> 23) - 127;                                   \
    a = acc * __int_as_float((127 - e_) << 23);                                   \
    eoff += e_ + eoffs[b * CH + (cc)];                                            \
} while (0)

    LOADW(bf0, 0); LOADW(bf1, 1); LOADW(bf2, 2);
    #pragma unroll 1
    for (int cj = 0; cj < CH; cj += 4) {
        LOADW(bf3, cj + 3); COMPW(bf0, cj);
        LOADW(bf0, cj + 4); COMPW(bf1, cj + 1);
        LOADW(bf1, cj + 5); COMPW(bf2, cj + 2);
        LOADW(bf2, cj + 6); COMPW(bf3, cj + 3);
    }
#undef COMPW
#undef LOADW

    // ---- logsumexp + res ----
    if (w == 0) {
        float v = a * exp2f(end_t[l] * LOG2E);
        #pragma unroll
        for (int sh = 1; sh < 64; sh <<= 1) v += __shfl_xor(v, sh, 64);
        float sct = (scpart[0] + scpart[1]) + (scpart[2] + scpart[3]);
        if (l == 0) res[b] = (log2f(v) + (float)eoff) * LN2 - sct;
    }
}

// ---------------- Phase 3: final mean ----------------
__global__ __launch_bounds__(64) void crf_reduce_kernel(
    const float* __restrict__ res, float* __restrict__ out)
{
    int l = threadIdx.x;
    float v = res[l] + res[l + 64];
    #pragma unroll
    for (int s = 1; s < 64; s <<= 1) v += __shfl_xor(v, s, 64);
    if (l == 0) out[0] = v * (1.0f / (float)BB);
}

extern "C" void kernel_launch(void* const* d_in, const int* in_sizes, int n_in,
                              void* d_out, int out_size, void* d_ws, size_t ws_size,
                              hipStream_t stream) {
    const float* emissions   = (const float*)d_in[0];
    const float* transitions = (const float*)d_in[1];
    const float* start_t     = (const float*)d_in[2];
    const float* end_t       = (const float*)d_in[3];
    const int*   tags        = (const int*)d_in[4];

    float* res   = (float*)d_ws;                               // 128 floats
    int*   eoffs = (int*)((char*)d_ws + 512);                  // <= 2048 ints
    unsigned short* atab = (unsigned short*)((char*)d_ws + 32768);  // 16 KB
    unsigned short* M = (unsigned short*)((char*)d_ws + 65536);

    crf_atab_kernel<<<1, 64, 0, stream>>>(transitions, atab);

    const size_t need16 = 65536 + (size_t)BB * 16 * TT * TT * 2;  // ~16.8 MB
    if (ws_size >= need16) {
        crf_chunk_kernel<16><<<BB * 4, 256, 0, stream>>>(emissions, atab, M, eoffs);
        crf_combine_kernel<16><<<BB, 256, 0, stream>>>(emissions, transitions, start_t,
                                                       end_t, tags, M, eoffs, res);
    } else {
        crf_chunk_kernel<8><<<BB * 2, 256, 0, stream>>>(emissions, atab, M, eoffs);
        crf_combine_kernel<8><<<BB, 256, 0, stream>>>(emissions, transitions, start_t,
                                                      end_t, tags, M, eoffs, res);
    }
    crf_reduce_kernel<<<1, 64, 0, stream>>>(res, (float*)d_out);
}